// Round 7
// baseline (520.311 us; speedup 1.0000x reference)
//
#include <hip/hip_runtime.h>
#include <hip/hip_bf16.h>

// Problem constants (match reference)
#define NN 50000
#define EE 800000
#define HH 128
#define GG 64

#define NB 196          // dst buckets = (50000>>8)+1
#define CHUNK 4096      // edges per partition block
#define NBLK ((EE + CHUNK - 1) / CHUNK)
#define CAP 8192        // LDS key capacity in k4
#define NPB 16          // nodes per agg block (4 waves x 4 nodes)
#define AGG_GRID ((NN + NPB - 1) / NPB)

typedef __attribute__((ext_vector_type(8))) short short8;
typedef __attribute__((ext_vector_type(4))) float f32x4;

__device__ __forceinline__ unsigned short f2bf(float f) {
    unsigned u = __float_as_uint(f);
    return (unsigned short)((u + 0x7FFFu + ((u >> 16) & 1u)) >> 16);  // RNE
}
__device__ __forceinline__ float bflo(unsigned p) { return __uint_as_float(p << 16); }
__device__ __forceinline__ float bfhi(unsigned p) { return __uint_as_float(p & 0xFFFF0000u); }

// ---------------- ws layout (bytes) ----------------
// zeroed region: [bhist NB][pooled G*HH f32]
#define OFF_BHIST   0                                        // NB ints
#define OFF_POOLED  (OFF_BHIST + NB*4)                       // GG*HH f32
#define ZERO_BYTES  (OFF_POOLED + GG*HH*4)
#define OFF_CURSOR  (ZERO_BYTES)                             // NB ints (init in k2)
#define OFF_BOFF    (OFF_CURSOR + NB*4)                      // NB+1 ints
#define OFF_GSTART  (OFF_BOFF + (NB+1)*4)                    // GG+1 ints
#define OFF_CSROFF  (((OFF_GSTART + (GG+1)*4) + 15)/16*16)   // NN+1 ints
#define OFF_DINV    (((OFF_CSROFF + (NN+1)*4) + 15)/16*16)   // NN f32
#define OFF_WT1     (((OFF_DINV + NN*4) + 15)/16*16)         // 128*128 bf16
#define OFF_WT2     (OFF_WT1 + HH*HH*2)                      // 128*128 bf16
#define OFF_KEYA    (OFF_WT2 + HH*HH*2)                      // EE u32
#define OFF_KEYB    (OFF_KEYA + EE*4)                        // EE u32
#define OFF_H       (OFF_KEYB + EE*4)                        // NN*128 bf16
#define OFF_G       (OFF_H + NN*HH*2)                        // NN*128 bf16

// ---------------- sort pipeline ----------------

__global__ __launch_bounds__(256) void k1_hist(
    const int* __restrict__ ei, int* __restrict__ bhist)
{
    __shared__ int h[NB];
    int tid = threadIdx.x;
    for (int j = tid; j < NB; j += 256) h[j] = 0;
    __syncthreads();
    int base = blockIdx.x * CHUNK;
    int end = min(base + CHUNK, EE);
    for (int i = base + tid; i < end; i += 256)
        atomicAdd(&h[ei[EE + i] >> 8], 1);
    __syncthreads();
    for (int j = tid; j < NB; j += 256)
        if (h[j]) atomicAdd(&bhist[j], h[j]);
}

__global__ __launch_bounds__(256) void k2_scan(
    const int* __restrict__ bhist, int* __restrict__ boff, int* __restrict__ cursor)
{
    __shared__ int v[NB + 1];
    int tid = threadIdx.x;
    if (tid < NB) v[tid] = bhist[tid];
    __syncthreads();
    if (tid == 0) {
        int run = 0;
        for (int j = 0; j < NB; ++j) { int t = v[j]; v[j] = run; run += t; }
        v[NB] = run;
    }
    __syncthreads();
    if (tid < NB) { boff[tid] = v[tid]; cursor[tid] = v[tid]; }
    if (tid == NB) boff[NB] = v[NB];
}

__global__ __launch_bounds__(256) void k3_scatter(
    const int* __restrict__ ei, int* __restrict__ cursor, unsigned* __restrict__ keyA)
{
    __shared__ int h[NB];
    __shared__ int basev[NB];
    __shared__ int c[NB];
    int tid = threadIdx.x;
    for (int j = tid; j < NB; j += 256) { h[j] = 0; c[j] = 0; }
    __syncthreads();
    int base = blockIdx.x * CHUNK;
    int end = min(base + CHUNK, EE);
    for (int i = base + tid; i < end; i += 256)
        atomicAdd(&h[ei[EE + i] >> 8], 1);
    __syncthreads();
    for (int j = tid; j < NB; j += 256)
        if (h[j]) basev[j] = atomicAdd(&cursor[j], h[j]);
    __syncthreads();
    for (int i = base + tid; i < end; i += 256) {
        int s = ei[i];
        int d = ei[EE + i];
        int b = d >> 8;
        int r = atomicAdd(&c[b], 1);               // LDS atomic
        keyA[basev[b] + r] = ((unsigned)d << 16) | (unsigned)s;
    }
}

__global__ __launch_bounds__(256) void k4_sort(
    const unsigned* __restrict__ keyA, const int* __restrict__ boff,
    unsigned* __restrict__ keyB, int* __restrict__ csr_off, float* __restrict__ dinv)
{
    __shared__ unsigned keys[CAP];
    __shared__ int h[256];
    __shared__ int off[256];
    int b = blockIdx.x, tid = threadIdx.x;
    int e0 = boff[b], e1 = boff[b + 1], n = e1 - e0;
    h[tid] = 0;
    __syncthreads();
    for (int i = tid; i < n; i += 256) {
        unsigned k = keyA[e0 + i];
        if (i < CAP) keys[i] = k;
        atomicAdd(&h[(k >> 16) & 255], 1);
    }
    __syncthreads();
    if (tid == 0) {
        int run = 0;
        for (int j = 0; j < 256; ++j) { int t = h[j]; off[j] = run; run += t; }
    }
    __syncthreads();
    int d = (b << 8) + tid;
    if (d < NN) {
        csr_off[d] = e0 + off[tid];
        dinv[d] = rsqrtf((float)(h[tid] + 1));     // +1 self loop
    }
    if (b == 0 && tid == 0) csr_off[NN] = EE;
    __syncthreads();
    h[tid] = 0;
    __syncthreads();
    for (int i = tid; i < n; i += 256) {
        unsigned k = (i < CAP) ? keys[i] : keyA[e0 + i];
        int lo = (k >> 16) & 255;
        int r = atomicAdd(&h[lo], 1);              // LDS atomic
        keyB[e0 + off[lo] + r] = k;
    }
}

__global__ __launch_bounds__(128) void gstart_kernel(
    const int* __restrict__ batch, int* __restrict__ gstart)
{
    int g = threadIdx.x;
    if (g > GG) return;
    int lo = 0, hi = NN;
    while (lo < hi) {
        int mid = (lo + hi) >> 1;
        if (batch[mid] < g) lo = mid + 1; else hi = mid;
    }
    gstart[g] = lo;
}

__global__ __launch_bounds__(256) void wcast_kernel(
    const float* __restrict__ W1, const float* __restrict__ W2,
    unsigned short* __restrict__ Wt1, unsigned short* __restrict__ Wt2)
{
    int i = blockIdx.x * 256 + threadIdx.x;
    if (i < HH * HH) {
        int r = i >> 7, c = i & 127;
        Wt1[c * HH + r] = f2bf(W1[i]);
        Wt2[c * HH + r] = f2bf(W2[i]);
    }
}

// ---------------- MFMA GEMM: C[row] = bf16((A[row] @ W) * dinv[row]) ----------------
template<bool F32SRC>
__global__ __launch_bounds__(256) void gemm_mfma_kernel(
    const void* __restrict__ Asrc, const unsigned short* __restrict__ Wt,
    const float* __restrict__ dinv, unsigned short* __restrict__ C)
{
    int tid = threadIdx.x;
    int w  = tid >> 6;       // wave -> col block
    int l  = tid & 63;
    int lr = l & 15;
    int lg = l >> 4;         // 0..3

    short8 bfrag[2][4];
    #pragma unroll
    for (int nt = 0; nt < 2; ++nt)
        #pragma unroll
        for (int kt = 0; kt < 4; ++kt) {
            int n = w * 32 + nt * 16 + lr;
            int k = kt * 32 + lg * 8;
            bfrag[nt][kt] = *(const short8*)(Wt + (size_t)n * HH + k);
        }

    int base0 = blockIdx.x * 64;
    #pragma unroll
    for (int mt = 0; mt < 4; ++mt) {
        int rowA = base0 + mt * 16 + lr;
        short8 afrag[4];
        #pragma unroll
        for (int kt = 0; kt < 4; ++kt) {
            short8 v = {0, 0, 0, 0, 0, 0, 0, 0};
            if (rowA < NN) {
                if (F32SRC) {
                    const float* p = (const float*)Asrc + (size_t)rowA * HH + kt * 32 + lg * 8;
                    f32x4 u0 = *(const f32x4*)p;
                    f32x4 u1 = *(const f32x4*)(p + 4);
                    #pragma unroll
                    for (int j = 0; j < 4; ++j) {
                        v[j]     = (short)f2bf(u0[j]);
                        v[j + 4] = (short)f2bf(u1[j]);
                    }
                } else {
                    v = *(const short8*)((const unsigned short*)Asrc +
                                         (size_t)rowA * HH + kt * 32 + lg * 8);
                }
            }
            afrag[kt] = v;
        }
        f32x4 acc0 = {0.f, 0.f, 0.f, 0.f};
        f32x4 acc1 = {0.f, 0.f, 0.f, 0.f};
        #pragma unroll
        for (int kt = 0; kt < 4; ++kt) {
            acc0 = __builtin_amdgcn_mfma_f32_16x16x32_bf16(afrag[kt], bfrag[0][kt], acc0, 0, 0, 0);
            acc1 = __builtin_amdgcn_mfma_f32_16x16x32_bf16(afrag[kt], bfrag[1][kt], acc1, 0, 0, 0);
        }
        #pragma unroll
        for (int r = 0; r < 4; ++r) {
            int row = base0 + mt * 16 + lg * 4 + r;
            if (row < NN) {
                float dn = dinv[row];
                C[(size_t)row * HH + w * 32 + lr]      = f2bf(acc0[r] * dn);
                C[(size_t)row * HH + w * 32 + 16 + lr] = f2bf(acc1[r] * dn);
            }
        }
    }
}

// ---------------- feature-split aggregation ----------------
// Pass p covers features [32p, 32p+32). 16 lanes per node (1 u32 = 2 bf16 each),
// 4 nodes/wave, 16 nodes/block. Gather working set per pass = 3.2 MB (fits L2).
// Layer 1: out[n] = bf16(relu(dn*(self+nbrs) + bias)), stored nontemporal.
__global__ __launch_bounds__(256) void agg1_pass_kernel(
    const unsigned* __restrict__ hp, const unsigned* __restrict__ keyB,
    const int* __restrict__ csr_off, const float* __restrict__ dinv,
    const float* __restrict__ bias, unsigned* __restrict__ out, int pass)
{
    int tid = threadIdx.x;
    int q  = tid >> 4;             // 0..15 node slot in block
    int fl = tid & 15;             // feature lane
    int node = (int)blockIdx.x * NPB + q;
    bool nv = node < NN;
    int nn = nv ? node : NN - 1;
    float dn = dinv[nn];
    int e  = nv ? csr_off[nn]     : 0;
    int e1 = nv ? csr_off[nn + 1] : 0;
    size_t rowoff = (size_t)(pass << 4) + fl;
    unsigned hv = hp[(size_t)nn * 64 + rowoff];
    float a0 = nv ? bflo(hv) : 0.f;     // self term (already dinv-scaled)
    float a1 = nv ? bfhi(hv) : 0.f;
    while (__any(e < e1)) {
        #pragma unroll
        for (int j = 0; j < 8; ++j) {
            bool act = (e + j) < e1;
            unsigned key = __builtin_nontemporal_load(&keyB[act ? (e + j) : 0]);
            int s = act ? (int)(key & 0xFFFF) : nn;
            unsigned v = hp[(size_t)s * 64 + rowoff];
            if (act) { a0 += bflo(v); a1 += bfhi(v); }
        }
        e += 8;
    }
    if (nv) {
        int f = (pass << 5) + (fl << 1);
        float o0 = fmaxf(a0 * dn + bias[f],     0.f);
        float o1 = fmaxf(a1 * dn + bias[f + 1], 0.f);
        unsigned po = (unsigned)f2bf(o0) | ((unsigned)f2bf(o1) << 16);
        __builtin_nontemporal_store(po, &out[(size_t)nn * 64 + rowoff]);
    }
}

// Layer 2 fused with mean-pool partial sums: o[n] = dn*(self+nbrs); accumulate
// o into pooled[batch[n]] via 2-slot LDS (block's 16 sorted nodes span <=2
// graphs almost always; >=3rd graph falls back to direct atomics).
__global__ __launch_bounds__(256) void agg2_pool_pass_kernel(
    const unsigned* __restrict__ hp, const unsigned* __restrict__ keyB,
    const int* __restrict__ csr_off, const float* __restrict__ dinv,
    const int* __restrict__ batch, float* __restrict__ pooled, int pass)
{
    __shared__ float pp[2][32];
    int tid = threadIdx.x;
    if (tid < 64) ((float*)pp)[tid] = 0.f;
    __syncthreads();
    int q  = tid >> 4;
    int fl = tid & 15;
    int node = (int)blockIdx.x * NPB + q;
    bool nv = node < NN;
    int nn = nv ? node : NN - 1;
    int b0idx = (int)blockIdx.x * NPB;
    if (b0idx > NN - 1) b0idx = NN - 1;
    int g0 = batch[b0idx];
    int gn = batch[nn];
    float dn = dinv[nn];
    int e  = nv ? csr_off[nn]     : 0;
    int e1 = nv ? csr_off[nn + 1] : 0;
    size_t rowoff = (size_t)(pass << 4) + fl;
    unsigned hv = hp[(size_t)nn * 64 + rowoff];
    float a0 = nv ? bflo(hv) : 0.f;
    float a1 = nv ? bfhi(hv) : 0.f;
    while (__any(e < e1)) {
        #pragma unroll
        for (int j = 0; j < 8; ++j) {
            bool act = (e + j) < e1;
            unsigned key = __builtin_nontemporal_load(&keyB[act ? (e + j) : 0]);
            int s = act ? (int)(key & 0xFFFF) : nn;
            unsigned v = hp[(size_t)s * 64 + rowoff];
            if (act) { a0 += bflo(v); a1 += bfhi(v); }
        }
        e += 8;
    }
    if (nv) {
        float o0 = a0 * dn, o1 = a1 * dn;
        int slot = gn - g0;
        if (slot <= 1) {
            atomicAdd(&pp[slot][fl * 2],     o0);   // LDS atomic
            atomicAdd(&pp[slot][fl * 2 + 1], o1);
        } else {                                    // rare: >=3rd graph in block
            atomicAdd(&pooled[(size_t)gn * HH + (pass << 5) + fl * 2],     o0);
            atomicAdd(&pooled[(size_t)gn * HH + (pass << 5) + fl * 2 + 1], o1);
        }
    }
    __syncthreads();
    if (tid < 32) {
        float v = pp[0][tid];
        if (v != 0.f) atomicAdd(&pooled[(size_t)g0 * HH + (pass << 5) + tid], v);
    } else if (tid < 64) {
        float v = pp[1][tid - 32];
        if (v != 0.f) atomicAdd(&pooled[(size_t)(g0 + 1) * HH + (pass << 5) + tid - 32], v);
    }
}

// out[g][f] = (pooled + cnt*b2[f]) / max(cnt,1)
__global__ __launch_bounds__(256) void finalize_kernel(
    const float* __restrict__ pooled, const int* __restrict__ gstart,
    const float* __restrict__ b2, float* __restrict__ out)
{
    int i = blockIdx.x * 256 + threadIdx.x;
    if (i < GG * HH) {
        int g = i >> 7;
        int f = i & 127;
        float cnt = (float)(gstart[g + 1] - gstart[g]);
        out[i] = (pooled[i] + cnt * b2[f]) / fmaxf(cnt, 1.f);
    }
}

// ---------------- launcher ----------------

extern "C" void kernel_launch(void* const* d_in, const int* in_sizes, int n_in,
                              void* d_out, int out_size, void* d_ws, size_t ws_size,
                              hipStream_t stream)
{
    const float* x     = (const float*)d_in[0];
    const int*   ei    = (const int*)d_in[1];
    const int*   batch = (const int*)d_in[2];
    const float* W1    = (const float*)d_in[3];
    const float* b1    = (const float*)d_in[4];
    const float* W2    = (const float*)d_in[5];
    const float* b2    = (const float*)d_in[6];
    float* out = (float*)d_out;

    char* ws = (char*)d_ws;
    int*            bhist   = (int*)(ws + OFF_BHIST);
    float*          pooled  = (float*)(ws + OFF_POOLED);
    int*            cursor  = (int*)(ws + OFF_CURSOR);
    int*            boff    = (int*)(ws + OFF_BOFF);
    int*            gstart  = (int*)(ws + OFF_GSTART);
    int*            csr_off = (int*)(ws + OFF_CSROFF);
    float*          dinv    = (float*)(ws + OFF_DINV);
    unsigned short* Wt1     = (unsigned short*)(ws + OFF_WT1);
    unsigned short* Wt2     = (unsigned short*)(ws + OFF_WT2);
    unsigned*       keyA    = (unsigned*)(ws + OFF_KEYA);
    unsigned*       keyB    = (unsigned*)(ws + OFF_KEYB);
    unsigned short* hbuf    = (unsigned short*)(ws + OFF_H);
    unsigned short* gbuf    = (unsigned short*)(ws + OFF_G);

    (void)hipMemsetAsync(ws, 0, ZERO_BYTES, stream);   // bhist + pooled

    // bucket sort by dst -> CSR + dinv
    k1_hist<<<NBLK, 256, 0, stream>>>(ei, bhist);
    k2_scan<<<1, 256, 0, stream>>>(bhist, boff, cursor);
    k3_scatter<<<NBLK, 256, 0, stream>>>(ei, cursor, keyA);
    k4_sort<<<NB, 256, 0, stream>>>(keyA, boff, keyB, csr_off, dinv);

    gstart_kernel<<<1, 128, 0, stream>>>(batch, gstart);
    wcast_kernel<<<(HH * HH + 255) / 256, 256, 0, stream>>>(W1, W2, Wt1, Wt2);

    // conv1: h' = bf16((x @ W1) * dinv); g = bf16(relu(dn*(self+nbrs) + b1))
    gemm_mfma_kernel<true><<<(NN + 63) / 64, 256, 0, stream>>>(x, Wt1, dinv, hbuf);
    for (int p = 0; p < 4; ++p)
        agg1_pass_kernel<<<AGG_GRID, 256, 0, stream>>>(
            (const unsigned*)hbuf, keyB, csr_off, dinv, b1, (unsigned*)gbuf, p);

    // conv2: h2' = bf16((g @ W2) * dinv); pooled += dn*(self+nbrs) per graph
    gemm_mfma_kernel<false><<<(NN + 63) / 64, 256, 0, stream>>>(gbuf, Wt2, dinv, hbuf);
    for (int p = 0; p < 4; ++p)
        agg2_pool_pass_kernel<<<AGG_GRID, 256, 0, stream>>>(
            (const unsigned*)hbuf, keyB, csr_off, dinv, batch, pooled, p);

    // out = (pooled + cnt*b2) / max(cnt,1)
    finalize_kernel<<<(GG * HH + 255) / 256, 256, 0, stream>>>(pooled, gstart, b2, out);
}

// Round 9
// 276.362 us; speedup vs baseline: 1.8827x; 1.8827x over previous
//
#include <hip/hip_runtime.h>
#include <hip/hip_bf16.h>

// Problem constants (match reference)
#define NN 50000
#define EE 800000
#define HH 128
#define GG 64

#define NB 196          // dst buckets = (50000>>8)+1
#define CHUNK 4096      // edges per partition block
#define NBLK ((EE + CHUNK - 1) / CHUNK)
#define CAP 8192        // LDS key capacity in k4
#define PSL 16          // row slices per graph in pool

typedef __attribute__((ext_vector_type(8))) short short8;
typedef __attribute__((ext_vector_type(4))) float f32x4;

__device__ __forceinline__ unsigned short f2bf(float f) {
    unsigned u = __float_as_uint(f);
    return (unsigned short)((u + 0x7FFFu + ((u >> 16) & 1u)) >> 16);  // RNE
}
__device__ __forceinline__ float bflo(unsigned p) { return __uint_as_float(p << 16); }
__device__ __forceinline__ float bfhi(unsigned p) { return __uint_as_float(p & 0xFFFF0000u); }
__device__ __forceinline__ float bfu(unsigned short u) { return __uint_as_float(((unsigned)u) << 16); }

// ---------------- ws layout (bytes) ----------------
// zeroed region: [bhist NB][pooled G*HH f32]
#define OFF_BHIST   0                                        // NB ints
#define OFF_POOLED  (OFF_BHIST + NB*4)                       // GG*HH f32
#define ZERO_BYTES  (OFF_POOLED + GG*HH*4)
#define OFF_CURSOR  (ZERO_BYTES)                             // NB ints (init in k2)
#define OFF_BOFF    (OFF_CURSOR + NB*4)                      // NB+1 ints
#define OFF_GSTART  (OFF_BOFF + (NB+1)*4)                    // GG+1 ints
#define OFF_CSROFF  (((OFF_GSTART + (GG+1)*4) + 15)/16*16)   // NN+1 ints
#define OFF_DINV    (((OFF_CSROFF + (NN+1)*4) + 15)/16*16)   // NN f32
#define OFF_WT1     (((OFF_DINV + NN*4) + 15)/16*16)         // 128*128 bf16
#define OFF_WT2     (OFF_WT1 + HH*HH*2)                      // 128*128 bf16
#define OFF_KEYA    (OFF_WT2 + HH*HH*2)                      // EE u32
#define OFF_KEYB    (OFF_KEYA + EE*4)                        // EE u32
#define OFF_H       (OFF_KEYB + EE*4)                        // NN*128 bf16
#define OFF_G       (OFF_H + NN*HH*2)                        // NN*128 bf16

// ---------------- sort pipeline ----------------

__global__ __launch_bounds__(256) void k1_hist(
    const int* __restrict__ ei, int* __restrict__ bhist)
{
    __shared__ int h[NB];
    int tid = threadIdx.x;
    for (int j = tid; j < NB; j += 256) h[j] = 0;
    __syncthreads();
    int base = blockIdx.x * CHUNK;
    int end = min(base + CHUNK, EE);
    for (int i = base + tid; i < end; i += 256)
        atomicAdd(&h[ei[EE + i] >> 8], 1);
    __syncthreads();
    for (int j = tid; j < NB; j += 256)
        if (h[j]) atomicAdd(&bhist[j], h[j]);
}

__global__ __launch_bounds__(256) void k2_scan(
    const int* __restrict__ bhist, int* __restrict__ boff, int* __restrict__ cursor)
{
    __shared__ int v[NB + 1];
    int tid = threadIdx.x;
    if (tid < NB) v[tid] = bhist[tid];
    __syncthreads();
    if (tid == 0) {
        int run = 0;
        for (int j = 0; j < NB; ++j) { int t = v[j]; v[j] = run; run += t; }
        v[NB] = run;
    }
    __syncthreads();
    if (tid < NB) { boff[tid] = v[tid]; cursor[tid] = v[tid]; }
    if (tid == NB) boff[NB] = v[NB];
}

__global__ __launch_bounds__(256) void k3_scatter(
    const int* __restrict__ ei, int* __restrict__ cursor, unsigned* __restrict__ keyA)
{
    __shared__ int h[NB];
    __shared__ int basev[NB];
    __shared__ int c[NB];
    int tid = threadIdx.x;
    for (int j = tid; j < NB; j += 256) { h[j] = 0; c[j] = 0; }
    __syncthreads();
    int base = blockIdx.x * CHUNK;
    int end = min(base + CHUNK, EE);
    for (int i = base + tid; i < end; i += 256)
        atomicAdd(&h[ei[EE + i] >> 8], 1);
    __syncthreads();
    for (int j = tid; j < NB; j += 256)
        if (h[j]) basev[j] = atomicAdd(&cursor[j], h[j]);
    __syncthreads();
    for (int i = base + tid; i < end; i += 256) {
        int s = ei[i];
        int d = ei[EE + i];
        int b = d >> 8;
        int r = atomicAdd(&c[b], 1);               // LDS atomic
        keyA[basev[b] + r] = ((unsigned)d << 16) | (unsigned)s;
    }
}

__global__ __launch_bounds__(256) void k4_sort(
    const unsigned* __restrict__ keyA, const int* __restrict__ boff,
    unsigned* __restrict__ keyB, int* __restrict__ csr_off, float* __restrict__ dinv)
{
    __shared__ unsigned keys[CAP];
    __shared__ int h[256];
    __shared__ int off[256];
    int b = blockIdx.x, tid = threadIdx.x;
    int e0 = boff[b], e1 = boff[b + 1], n = e1 - e0;
    h[tid] = 0;
    __syncthreads();
    for (int i = tid; i < n; i += 256) {
        unsigned k = keyA[e0 + i];
        if (i < CAP) keys[i] = k;
        atomicAdd(&h[(k >> 16) & 255], 1);
    }
    __syncthreads();
    if (tid == 0) {
        int run = 0;
        for (int j = 0; j < 256; ++j) { int t = h[j]; off[j] = run; run += t; }
    }
    __syncthreads();
    int d = (b << 8) + tid;
    if (d < NN) {
        csr_off[d] = e0 + off[tid];
        dinv[d] = rsqrtf((float)(h[tid] + 1));     // +1 self loop
    }
    if (b == 0 && tid == 0) csr_off[NN] = EE;
    __syncthreads();
    h[tid] = 0;
    __syncthreads();
    for (int i = tid; i < n; i += 256) {
        unsigned k = (i < CAP) ? keys[i] : keyA[e0 + i];
        int lo = (k >> 16) & 255;
        int r = atomicAdd(&h[lo], 1);              // LDS atomic
        keyB[e0 + off[lo] + r] = k;
    }
}

__global__ __launch_bounds__(128) void gstart_kernel(
    const int* __restrict__ batch, int* __restrict__ gstart)
{
    int g = threadIdx.x;
    if (g > GG) return;
    int lo = 0, hi = NN;
    while (lo < hi) {
        int mid = (lo + hi) >> 1;
        if (batch[mid] < g) lo = mid + 1; else hi = mid;
    }
    gstart[g] = lo;
}

__global__ __launch_bounds__(256) void wcast_kernel(
    const float* __restrict__ W1, const float* __restrict__ W2,
    unsigned short* __restrict__ Wt1, unsigned short* __restrict__ Wt2)
{
    int i = blockIdx.x * 256 + threadIdx.x;
    if (i < HH * HH) {
        int r = i >> 7, c = i & 127;
        Wt1[c * HH + r] = f2bf(W1[i]);
        Wt2[c * HH + r] = f2bf(W2[i]);
    }
}

// ---------------- MFMA GEMM: C[row] = bf16((A[row] @ W) * dinv[row]) ----------------
template<bool F32SRC>
__global__ __launch_bounds__(256) void gemm_mfma_kernel(
    const void* __restrict__ Asrc, const unsigned short* __restrict__ Wt,
    const float* __restrict__ dinv, unsigned short* __restrict__ C)
{
    int tid = threadIdx.x;
    int w  = tid >> 6;       // wave -> col block
    int l  = tid & 63;
    int lr = l & 15;
    int lg = l >> 4;         // 0..3

    short8 bfrag[2][4];
    #pragma unroll
    for (int nt = 0; nt < 2; ++nt)
        #pragma unroll
        for (int kt = 0; kt < 4; ++kt) {
            int n = w * 32 + nt * 16 + lr;
            int k = kt * 32 + lg * 8;
            bfrag[nt][kt] = *(const short8*)(Wt + (size_t)n * HH + k);
        }

    int base0 = blockIdx.x * 64;
    #pragma unroll
    for (int mt = 0; mt < 4; ++mt) {
        int rowA = base0 + mt * 16 + lr;
        short8 afrag[4];
        #pragma unroll
        for (int kt = 0; kt < 4; ++kt) {
            short8 v = {0, 0, 0, 0, 0, 0, 0, 0};
            if (rowA < NN) {
                if (F32SRC) {
                    const float* p = (const float*)Asrc + (size_t)rowA * HH + kt * 32 + lg * 8;
                    f32x4 u0 = *(const f32x4*)p;
                    f32x4 u1 = *(const f32x4*)(p + 4);
                    #pragma unroll
                    for (int j = 0; j < 4; ++j) {
                        v[j]     = (short)f2bf(u0[j]);
                        v[j + 4] = (short)f2bf(u1[j]);
                    }
                } else {
                    v = *(const short8*)((const unsigned short*)Asrc +
                                         (size_t)rowA * HH + kt * 32 + lg * 8);
                }
            }
            afrag[kt] = v;
        }
        f32x4 acc0 = {0.f, 0.f, 0.f, 0.f};
        f32x4 acc1 = {0.f, 0.f, 0.f, 0.f};
        #pragma unroll
        for (int kt = 0; kt < 4; ++kt) {
            acc0 = __builtin_amdgcn_mfma_f32_16x16x32_bf16(afrag[kt], bfrag[0][kt], acc0, 0, 0, 0);
            acc1 = __builtin_amdgcn_mfma_f32_16x16x32_bf16(afrag[kt], bfrag[1][kt], acc1, 0, 0, 0);
        }
        #pragma unroll
        for (int r = 0; r < 4; ++r) {
            int row = base0 + mt * 16 + lg * 4 + r;
            if (row < NN) {
                float dn = dinv[row];
                C[(size_t)row * HH + w * 32 + lr]      = f2bf(acc0[r] * dn);
                C[(size_t)row * HH + w * 32 + 16 + lr] = f2bf(acc1[r] * dn);
            }
        }
    }
}

// ---------------- aggregation (full bf16 rows, f32 accumulate) ----------------
// sum = h'[n] + sum_{s in N(n)} h'[s];  out = FIN ? relu(dn*sum + bias) : dn*sum
// one wave per node, lane = 2 features (u32); edge loop unrolled x8 for MLP.
template<bool FIN>
__global__ __launch_bounds__(256) void agg_kernel(
    const unsigned* __restrict__ hp, const unsigned* __restrict__ keyB,
    const int* __restrict__ csr_off, const float* __restrict__ dinv,
    const float* __restrict__ bias, unsigned* __restrict__ out)
{
    int node = (int)blockIdx.x * 4 + (threadIdx.x >> 6);
    if (node >= NN) return;
    int lane = threadIdx.x & 63;
    float dn = dinv[node];
    unsigned hv = hp[(size_t)node * 64 + lane];
    float ax = bflo(hv), ay = bfhi(hv);       // self term (already dinv-scaled)
    int e = csr_off[node], e1 = csr_off[node + 1];
    for (; e + 8 <= e1; e += 8) {
        int s0 = (int)(__builtin_nontemporal_load(&keyB[e])     & 0xFFFF);
        int s1 = (int)(__builtin_nontemporal_load(&keyB[e + 1]) & 0xFFFF);
        int s2 = (int)(__builtin_nontemporal_load(&keyB[e + 2]) & 0xFFFF);
        int s3 = (int)(__builtin_nontemporal_load(&keyB[e + 3]) & 0xFFFF);
        int s4 = (int)(__builtin_nontemporal_load(&keyB[e + 4]) & 0xFFFF);
        int s5 = (int)(__builtin_nontemporal_load(&keyB[e + 5]) & 0xFFFF);
        int s6 = (int)(__builtin_nontemporal_load(&keyB[e + 6]) & 0xFFFF);
        int s7 = (int)(__builtin_nontemporal_load(&keyB[e + 7]) & 0xFFFF);
        unsigned v0 = hp[(size_t)s0 * 64 + lane];
        unsigned v1 = hp[(size_t)s1 * 64 + lane];
        unsigned v2 = hp[(size_t)s2 * 64 + lane];
        unsigned v3 = hp[(size_t)s3 * 64 + lane];
        unsigned v4 = hp[(size_t)s4 * 64 + lane];
        unsigned v5 = hp[(size_t)s5 * 64 + lane];
        unsigned v6 = hp[(size_t)s6 * 64 + lane];
        unsigned v7 = hp[(size_t)s7 * 64 + lane];
        ax += (bflo(v0) + bflo(v1)) + (bflo(v2) + bflo(v3))
            + (bflo(v4) + bflo(v5)) + (bflo(v6) + bflo(v7));
        ay += (bfhi(v0) + bfhi(v1)) + (bfhi(v2) + bfhi(v3))
            + (bfhi(v4) + bfhi(v5)) + (bfhi(v6) + bfhi(v7));
    }
    for (; e < e1; ++e) {
        int s = (int)(__builtin_nontemporal_load(&keyB[e]) & 0xFFFF);
        unsigned v = hp[(size_t)s * 64 + lane];
        ax += bflo(v);
        ay += bfhi(v);
    }
    float ox = ax * dn, oy = ay * dn;
    if (FIN) {
        ox = fmaxf(ox + bias[lane * 2],     0.f);
        oy = fmaxf(oy + bias[lane * 2 + 1], 0.f);
    }
    unsigned po = (unsigned)f2bf(ox) | ((unsigned)f2bf(oy) << 16);
    __builtin_nontemporal_store(po, &out[(size_t)node * 64 + lane]);
}

// parallel segmented pool: block (g, slice) sums rows n = s_g+slice, +PSL, ...
// thread = one feature; one hot atomicAdd per (block, feature).
__global__ __launch_bounds__(128) void pool2_kernel(
    const unsigned short* __restrict__ h3, const int* __restrict__ gstart,
    float* __restrict__ pooled)
{
    int g  = (int)blockIdx.x >> 4;       // graph
    int sl = (int)blockIdx.x & (PSL - 1);
    int f  = threadIdx.x;
    int s = gstart[g], e = gstart[g + 1];
    float a0 = 0.f, a1 = 0.f, a2 = 0.f, a3 = 0.f;
    int n = s + sl;
    for (; n + 3 * PSL < e; n += 4 * PSL) {
        a0 += bfu(h3[(size_t)n * HH + f]);
        a1 += bfu(h3[(size_t)(n + PSL) * HH + f]);
        a2 += bfu(h3[(size_t)(n + 2 * PSL) * HH + f]);
        a3 += bfu(h3[(size_t)(n + 3 * PSL) * HH + f]);
    }
    for (; n < e; n += PSL) a0 += bfu(h3[(size_t)n * HH + f]);
    float acc = (a0 + a1) + (a2 + a3);
    if (acc != 0.f) atomicAdd(&pooled[(size_t)g * HH + f], acc);
}

// out[g][f] = (pooled + cnt*b2[f]) / max(cnt,1)
__global__ __launch_bounds__(256) void finalize_kernel(
    const float* __restrict__ pooled, const int* __restrict__ gstart,
    const float* __restrict__ b2, float* __restrict__ out)
{
    int i = blockIdx.x * 256 + threadIdx.x;
    if (i < GG * HH) {
        int g = i >> 7;
        int f = i & 127;
        float cnt = (float)(gstart[g + 1] - gstart[g]);
        out[i] = (pooled[i] + cnt * b2[f]) / fmaxf(cnt, 1.f);
    }
}

// ---------------- launcher ----------------

extern "C" void kernel_launch(void* const* d_in, const int* in_sizes, int n_in,
                              void* d_out, int out_size, void* d_ws, size_t ws_size,
                              hipStream_t stream)
{
    const float* x     = (const float*)d_in[0];
    const int*   ei    = (const int*)d_in[1];
    const int*   batch = (const int*)d_in[2];
    const float* W1    = (const float*)d_in[3];
    const float* b1    = (const float*)d_in[4];
    const float* W2    = (const float*)d_in[5];
    const float* b2    = (const float*)d_in[6];
    float* out = (float*)d_out;

    char* ws = (char*)d_ws;
    int*            bhist   = (int*)(ws + OFF_BHIST);
    float*          pooled  = (float*)(ws + OFF_POOLED);
    int*            cursor  = (int*)(ws + OFF_CURSOR);
    int*            boff    = (int*)(ws + OFF_BOFF);
    int*            gstart  = (int*)(ws + OFF_GSTART);
    int*            csr_off = (int*)(ws + OFF_CSROFF);
    float*          dinv    = (float*)(ws + OFF_DINV);
    unsigned short* Wt1     = (unsigned short*)(ws + OFF_WT1);
    unsigned short* Wt2     = (unsigned short*)(ws + OFF_WT2);
    unsigned*       keyA    = (unsigned*)(ws + OFF_KEYA);
    unsigned*       keyB    = (unsigned*)(ws + OFF_KEYB);
    unsigned short* hbuf    = (unsigned short*)(ws + OFF_H);
    unsigned short* gbuf    = (unsigned short*)(ws + OFF_G);

    (void)hipMemsetAsync(ws, 0, ZERO_BYTES, stream);   // bhist + pooled

    // bucket sort by dst -> CSR + dinv
    k1_hist<<<NBLK, 256, 0, stream>>>(ei, bhist);
    k2_scan<<<1, 256, 0, stream>>>(bhist, boff, cursor);
    k3_scatter<<<NBLK, 256, 0, stream>>>(ei, cursor, keyA);
    k4_sort<<<NB, 256, 0, stream>>>(keyA, boff, keyB, csr_off, dinv);

    gstart_kernel<<<1, 128, 0, stream>>>(batch, gstart);
    wcast_kernel<<<(HH * HH + 255) / 256, 256, 0, stream>>>(W1, W2, Wt1, Wt2);

    // conv1: h' = bf16((x @ W1) * dinv); g = bf16(relu(dn*(self+nbrs) + b1))
    gemm_mfma_kernel<true><<<(NN + 63) / 64, 256, 0, stream>>>(x, Wt1, dinv, hbuf);
    agg_kernel<true><<<(NN + 3) / 4, 256, 0, stream>>>(
        (const unsigned*)hbuf, keyB, csr_off, dinv, b1, (unsigned*)gbuf);

    // conv2: h2' = bf16((g @ W2) * dinv); h3 = bf16(dn*(self+nbrs))
    gemm_mfma_kernel<false><<<(NN + 63) / 64, 256, 0, stream>>>(gbuf, Wt2, dinv, hbuf);
    agg_kernel<false><<<(NN + 3) / 4, 256, 0, stream>>>(
        (const unsigned*)hbuf, keyB, csr_off, dinv, b2, (unsigned*)gbuf);

    // mean pool: parallel partial sums + finalize
    pool2_kernel<<<GG * PSL, 128, 0, stream>>>(gbuf, gstart, pooled);
    finalize_kernel<<<(GG * HH + 255) / 256, 256, 0, stream>>>(pooled, gstart, b2, out);
}

// Round 11
// 267.905 us; speedup vs baseline: 1.9421x; 1.0316x over previous
//
#include <hip/hip_runtime.h>
#include <hip/hip_bf16.h>

// Problem constants (match reference)
#define NN 50000
#define EE 800000
#define HH 128
#define GG 64

#define NB 196          // dst buckets = (50000>>8)+1
#define CHUNK 4096      // edges per partition block
#define NBLK ((EE + CHUNK - 1) / CHUNK)
#define CAP 8192        // LDS key capacity in k4
#define PSL 16          // row slices per graph in pool

typedef __attribute__((ext_vector_type(8))) short short8;
typedef __attribute__((ext_vector_type(4))) float f32x4;

__device__ __forceinline__ unsigned short f2bf(float f) {
    unsigned u = __float_as_uint(f);
    return (unsigned short)((u + 0x7FFFu + ((u >> 16) & 1u)) >> 16);  // RNE
}
__device__ __forceinline__ float bflo(unsigned p) { return __uint_as_float(p << 16); }
__device__ __forceinline__ float bfhi(unsigned p) { return __uint_as_float(p & 0xFFFF0000u); }
__device__ __forceinline__ float bfu(unsigned short u) { return __uint_as_float(((unsigned)u) << 16); }

// ---------------- ws layout (bytes) ----------------
// zeroed region: [bhist NB][pooled G*HH f32]
#define OFF_BHIST   0                                        // NB ints
#define OFF_POOLED  (OFF_BHIST + NB*4)                       // GG*HH f32
#define ZERO_BYTES  (OFF_POOLED + GG*HH*4)
#define OFF_CURSOR  (ZERO_BYTES)                             // NB ints (init in k2)
#define OFF_BOFF    (OFF_CURSOR + NB*4)                      // NB+1 ints
#define OFF_GSTART  (OFF_BOFF + (NB+1)*4)                    // GG+1 ints
#define OFF_CSROFF  (((OFF_GSTART + (GG+1)*4) + 15)/16*16)   // NN+1 ints
#define OFF_DINV    (((OFF_CSROFF + (NN+1)*4) + 15)/16*16)   // NN f32
#define OFF_WT1     (((OFF_DINV + NN*4) + 15)/16*16)         // 128*128 bf16
#define OFF_WT2     (OFF_WT1 + HH*HH*2)                      // 128*128 bf16
#define OFF_KEYA    (OFF_WT2 + HH*HH*2)                      // EE u32
#define OFF_KEYB    (OFF_KEYA + EE*4)                        // EE u32
#define OFF_H       (OFF_KEYB + EE*4)                        // NN*128 bf16
#define OFF_G       (OFF_H + NN*HH*2)                        // NN*128 bf16

// ---------------- sort pipeline ----------------

__global__ __launch_bounds__(256) void k1_hist(
    const int* __restrict__ ei, int* __restrict__ bhist)
{
    __shared__ int h[NB];
    int tid = threadIdx.x;
    for (int j = tid; j < NB; j += 256) h[j] = 0;
    __syncthreads();
    int base = blockIdx.x * CHUNK;
    int end = min(base + CHUNK, EE);
    for (int i = base + tid; i < end; i += 256)
        atomicAdd(&h[ei[EE + i] >> 8], 1);
    __syncthreads();
    for (int j = tid; j < NB; j += 256)
        if (h[j]) atomicAdd(&bhist[j], h[j]);
}

__global__ __launch_bounds__(256) void k2_scan(
    const int* __restrict__ bhist, int* __restrict__ boff, int* __restrict__ cursor)
{
    __shared__ int v[NB + 1];
    int tid = threadIdx.x;
    if (tid < NB) v[tid] = bhist[tid];
    __syncthreads();
    if (tid == 0) {
        int run = 0;
        for (int j = 0; j < NB; ++j) { int t = v[j]; v[j] = run; run += t; }
        v[NB] = run;
    }
    __syncthreads();
    if (tid < NB) { boff[tid] = v[tid]; cursor[tid] = v[tid]; }
    if (tid == NB) boff[NB] = v[NB];
}

__global__ __launch_bounds__(256) void k3_scatter(
    const int* __restrict__ ei, int* __restrict__ cursor, unsigned* __restrict__ keyA)
{
    __shared__ int h[NB];
    __shared__ int basev[NB];
    __shared__ int c[NB];
    int tid = threadIdx.x;
    for (int j = tid; j < NB; j += 256) { h[j] = 0; c[j] = 0; }
    __syncthreads();
    int base = blockIdx.x * CHUNK;
    int end = min(base + CHUNK, EE);
    for (int i = base + tid; i < end; i += 256)
        atomicAdd(&h[ei[EE + i] >> 8], 1);
    __syncthreads();
    for (int j = tid; j < NB; j += 256)
        if (h[j]) basev[j] = atomicAdd(&cursor[j], h[j]);
    __syncthreads();
    for (int i = base + tid; i < end; i += 256) {
        int s = ei[i];
        int d = ei[EE + i];
        int b = d >> 8;
        int r = atomicAdd(&c[b], 1);               // LDS atomic
        keyA[basev[b] + r] = ((unsigned)d << 16) | (unsigned)s;
    }
}

__global__ __launch_bounds__(256) void k4_sort(
    const unsigned* __restrict__ keyA, const int* __restrict__ boff,
    unsigned* __restrict__ keyB, int* __restrict__ csr_off, float* __restrict__ dinv)
{
    __shared__ unsigned keys[CAP];
    __shared__ int h[256];
    __shared__ int off[256];
    int b = blockIdx.x, tid = threadIdx.x;
    int e0 = boff[b], e1 = boff[b + 1], n = e1 - e0;
    h[tid] = 0;
    __syncthreads();
    for (int i = tid; i < n; i += 256) {
        unsigned k = keyA[e0 + i];
        if (i < CAP) keys[i] = k;
        atomicAdd(&h[(k >> 16) & 255], 1);
    }
    __syncthreads();
    if (tid == 0) {
        int run = 0;
        for (int j = 0; j < 256; ++j) { int t = h[j]; off[j] = run; run += t; }
    }
    __syncthreads();
    int d = (b << 8) + tid;
    if (d < NN) {
        csr_off[d] = e0 + off[tid];
        dinv[d] = rsqrtf((float)(h[tid] + 1));     // +1 self loop
    }
    if (b == 0 && tid == 0) csr_off[NN] = EE;
    __syncthreads();
    h[tid] = 0;
    __syncthreads();
    for (int i = tid; i < n; i += 256) {
        unsigned k = (i < CAP) ? keys[i] : keyA[e0 + i];
        int lo = (k >> 16) & 255;
        int r = atomicAdd(&h[lo], 1);              // LDS atomic
        keyB[e0 + off[lo] + r] = k;
    }
}

__global__ __launch_bounds__(128) void gstart_kernel(
    const int* __restrict__ batch, int* __restrict__ gstart)
{
    int g = threadIdx.x;
    if (g > GG) return;
    int lo = 0, hi = NN;
    while (lo < hi) {
        int mid = (lo + hi) >> 1;
        if (batch[mid] < g) lo = mid + 1; else hi = mid;
    }
    gstart[g] = lo;
}

__global__ __launch_bounds__(256) void wcast_kernel(
    const float* __restrict__ W1, const float* __restrict__ W2,
    unsigned short* __restrict__ Wt1, unsigned short* __restrict__ Wt2)
{
    int i = blockIdx.x * 256 + threadIdx.x;
    if (i < HH * HH) {
        int r = i >> 7, c = i & 127;
        Wt1[c * HH + r] = f2bf(W1[i]);
        Wt2[c * HH + r] = f2bf(W2[i]);
    }
}

// ---------------- MFMA GEMM: C[row] = bf16((A[row] @ W) * dinv[row]) ----------------
template<bool F32SRC>
__global__ __launch_bounds__(256) void gemm_mfma_kernel(
    const void* __restrict__ Asrc, const unsigned short* __restrict__ Wt,
    const float* __restrict__ dinv, unsigned short* __restrict__ C)
{
    int tid = threadIdx.x;
    int w  = tid >> 6;       // wave -> col block
    int l  = tid & 63;
    int lr = l & 15;
    int lg = l >> 4;         // 0..3

    short8 bfrag[2][4];
    #pragma unroll
    for (int nt = 0; nt < 2; ++nt)
        #pragma unroll
        for (int kt = 0; kt < 4; ++kt) {
            int n = w * 32 + nt * 16 + lr;
            int k = kt * 32 + lg * 8;
            bfrag[nt][kt] = *(const short8*)(Wt + (size_t)n * HH + k);
        }

    int base0 = blockIdx.x * 64;
    #pragma unroll
    for (int mt = 0; mt < 4; ++mt) {
        int rowA = base0 + mt * 16 + lr;
        short8 afrag[4];
        #pragma unroll
        for (int kt = 0; kt < 4; ++kt) {
            short8 v = {0, 0, 0, 0, 0, 0, 0, 0};
            if (rowA < NN) {
                if (F32SRC) {
                    const float* p = (const float*)Asrc + (size_t)rowA * HH + kt * 32 + lg * 8;
                    f32x4 u0 = *(const f32x4*)p;
                    f32x4 u1 = *(const f32x4*)(p + 4);
                    #pragma unroll
                    for (int j = 0; j < 4; ++j) {
                        v[j]     = (short)f2bf(u0[j]);
                        v[j + 4] = (short)f2bf(u1[j]);
                    }
                } else {
                    v = *(const short8*)((const unsigned short*)Asrc +
                                         (size_t)rowA * HH + kt * 32 + lg * 8);
                }
            }
            afrag[kt] = v;
        }
        f32x4 acc0 = {0.f, 0.f, 0.f, 0.f};
        f32x4 acc1 = {0.f, 0.f, 0.f, 0.f};
        #pragma unroll
        for (int kt = 0; kt < 4; ++kt) {
            acc0 = __builtin_amdgcn_mfma_f32_16x16x32_bf16(afrag[kt], bfrag[0][kt], acc0, 0, 0, 0);
            acc1 = __builtin_amdgcn_mfma_f32_16x16x32_bf16(afrag[kt], bfrag[1][kt], acc1, 0, 0, 0);
        }
        #pragma unroll
        for (int r = 0; r < 4; ++r) {
            int row = base0 + mt * 16 + lg * 4 + r;
            if (row < NN) {
                float dn = dinv[row];
                C[(size_t)row * HH + w * 32 + lr]      = f2bf(acc0[r] * dn);
                C[(size_t)row * HH + w * 32 + 16 + lr] = f2bf(acc1[r] * dn);
            }
        }
    }
}

// ---------------- aggregation (full bf16 rows, f32 accumulate) ----------------
// sum = h'[n] + sum_{s in N(n)} h'[s];  out = FIN ? relu(dn*sum + bias) : dn*sum
// one wave per node, lane = 2 features (u32). Fixed 8-slot PREDICATED loop:
// every iteration issues 8 key loads + 8 gathers (no serial tail). Inactive
// slots clamp the key index and gather the node's own (L1-hot) row, then are
// predicated off in the accumulate. All conditions are wave-uniform.
template<bool FIN>
__global__ __launch_bounds__(256) void agg_kernel(
    const unsigned* __restrict__ hp, const unsigned* __restrict__ keyB,
    const int* __restrict__ csr_off, const float* __restrict__ dinv,
    const float* __restrict__ bias, unsigned* __restrict__ out)
{
    int node = (int)blockIdx.x * 4 + (threadIdx.x >> 6);
    if (node >= NN) return;
    int lane = threadIdx.x & 63;
    float dn = dinv[node];
    unsigned hv = hp[(size_t)node * 64 + lane];
    float ax = bflo(hv), ay = bfhi(hv);       // self term (already dinv-scaled)
    int e0 = csr_off[node], e1 = csr_off[node + 1];
    for (int base = e0; base < e1; base += 8) {
        unsigned kk[8];
        #pragma unroll
        for (int j = 0; j < 8; ++j) {
            int ee = base + j;
            int ce = (ee < e1) ? ee : (e1 - 1);
            kk[j] = __builtin_nontemporal_load(&keyB[ce]);
        }
        unsigned vv[8];
        #pragma unroll
        for (int j = 0; j < 8; ++j) {
            int s = (base + j < e1) ? (int)(kk[j] & 0xFFFF) : node;
            vv[j] = hp[(size_t)s * 64 + lane];
        }
        float bx0 = 0.f, bx1 = 0.f, by0 = 0.f, by1 = 0.f;
        #pragma unroll
        for (int j = 0; j < 8; ++j) {
            if (base + j < e1) {
                if (j & 1) { bx1 += bflo(vv[j]); by1 += bfhi(vv[j]); }
                else       { bx0 += bflo(vv[j]); by0 += bfhi(vv[j]); }
            }
        }
        ax += bx0 + bx1;
        ay += by0 + by1;
    }
    float ox = ax * dn, oy = ay * dn;
    if (FIN) {
        ox = fmaxf(ox + bias[lane * 2],     0.f);
        oy = fmaxf(oy + bias[lane * 2 + 1], 0.f);
    }
    unsigned po = (unsigned)f2bf(ox) | ((unsigned)f2bf(oy) << 16);
    __builtin_nontemporal_store(po, &out[(size_t)node * 64 + lane]);
}

// parallel segmented pool: block (g, slice) sums rows n = s_g+slice, +PSL, ...
// thread = one feature; one hot atomicAdd per (block, feature).
__global__ __launch_bounds__(128) void pool2_kernel(
    const unsigned short* __restrict__ h3, const int* __restrict__ gstart,
    float* __restrict__ pooled)
{
    int g  = (int)blockIdx.x >> 4;       // graph
    int sl = (int)blockIdx.x & (PSL - 1);
    int f  = threadIdx.x;
    int s = gstart[g], e = gstart[g + 1];
    float a0 = 0.f, a1 = 0.f, a2 = 0.f, a3 = 0.f;
    int n = s + sl;
    for (; n + 3 * PSL < e; n += 4 * PSL) {
        a0 += bfu(h3[(size_t)n * HH + f]);
        a1 += bfu(h3[(size_t)(n + PSL) * HH + f]);
        a2 += bfu(h3[(size_t)(n + 2 * PSL) * HH + f]);
        a3 += bfu(h3[(size_t)(n + 3 * PSL) * HH + f]);
    }
    for (; n < e; n += PSL) a0 += bfu(h3[(size_t)n * HH + f]);
    float acc = (a0 + a1) + (a2 + a3);
    if (acc != 0.f) atomicAdd(&pooled[(size_t)g * HH + f], acc);
}

// out[g][f] = (pooled + cnt*b2[f]) / max(cnt,1)
__global__ __launch_bounds__(256) void finalize_kernel(
    const float* __restrict__ pooled, const int* __restrict__ gstart,
    const float* __restrict__ b2, float* __restrict__ out)
{
    int i = blockIdx.x * 256 + threadIdx.x;
    if (i < GG * HH) {
        int g = i >> 7;
        int f = i & 127;
        float cnt = (float)(gstart[g + 1] - gstart[g]);
        out[i] = (pooled[i] + cnt * b2[f]) / fmaxf(cnt, 1.f);
    }
}

// ---------------- launcher ----------------

extern "C" void kernel_launch(void* const* d_in, const int* in_sizes, int n_in,
                              void* d_out, int out_size, void* d_ws, size_t ws_size,
                              hipStream_t stream)
{
    const float* x     = (const float*)d_in[0];
    const int*   ei    = (const int*)d_in[1];
    const int*   batch = (const int*)d_in[2];
    const float* W1    = (const float*)d_in[3];
    const float* b1    = (const float*)d_in[4];
    const float* W2    = (const float*)d_in[5];
    const float* b2    = (const float*)d_in[6];
    float* out = (float*)d_out;

    char* ws = (char*)d_ws;
    int*            bhist   = (int*)(ws + OFF_BHIST);
    float*          pooled  = (float*)(ws + OFF_POOLED);
    int*            cursor  = (int*)(ws + OFF_CURSOR);
    int*            boff    = (int*)(ws + OFF_BOFF);
    int*            gstart  = (int*)(ws + OFF_GSTART);
    int*            csr_off = (int*)(ws + OFF_CSROFF);
    float*          dinv    = (float*)(ws + OFF_DINV);
    unsigned short* Wt1     = (unsigned short*)(ws + OFF_WT1);
    unsigned short* Wt2     = (unsigned short*)(ws + OFF_WT2);
    unsigned*       keyA    = (unsigned*)(ws + OFF_KEYA);
    unsigned*       keyB    = (unsigned*)(ws + OFF_KEYB);
    unsigned short* hbuf    = (unsigned short*)(ws + OFF_H);
    unsigned short* gbuf    = (unsigned short*)(ws + OFF_G);

    (void)hipMemsetAsync(ws, 0, ZERO_BYTES, stream);   // bhist + pooled

    // bucket sort by dst -> CSR + dinv
    k1_hist<<<NBLK, 256, 0, stream>>>(ei, bhist);
    k2_scan<<<1, 256, 0, stream>>>(bhist, boff, cursor);
    k3_scatter<<<NBLK, 256, 0, stream>>>(ei, cursor, keyA);
    k4_sort<<<NB, 256, 0, stream>>>(keyA, boff, keyB, csr_off, dinv);

    gstart_kernel<<<1, 128, 0, stream>>>(batch, gstart);
    wcast_kernel<<<(HH * HH + 255) / 256, 256, 0, stream>>>(W1, W2, Wt1, Wt2);

    // conv1: h' = bf16((x @ W1) * dinv); g = bf16(relu(dn*(self+nbrs) + b1))
    gemm_mfma_kernel<true><<<(NN + 63) / 64, 256, 0, stream>>>(x, Wt1, dinv, hbuf);
    agg_kernel<true><<<(NN + 3) / 4, 256, 0, stream>>>(
        (const unsigned*)hbuf, keyB, csr_off, dinv, b1, (unsigned*)gbuf);

    // conv2: h2' = bf16((g @ W2) * dinv); h3 = bf16(dn*(self+nbrs))
    gemm_mfma_kernel<false><<<(NN + 63) / 64, 256, 0, stream>>>(gbuf, Wt2, dinv, hbuf);
    agg_kernel<false><<<(NN + 3) / 4, 256, 0, stream>>>(
        (const unsigned*)hbuf, keyB, csr_off, dinv, b2, (unsigned*)gbuf);

    // mean pool: parallel partial sums + finalize
    pool2_kernel<<<GG * PSL, 128, 0, stream>>>(gbuf, gstart, pooled);
    finalize_kernel<<<(GG * HH + 255) / 256, 256, 0, stream>>>(pooled, gstart, b2, out);
}